// Round 16
// baseline (114.001 us; speedup 1.0000x reference)
//
#include <hip/hip_runtime.h>
#include <hip/hip_bf16.h>

#define EPSV 1e-5f
#define DW_THR 4.0f
#define PW_THR 1e-3f

static constexpr int BB = 32, CIN = 256, COUT = 512, HH = 56, WW = 56, HW = HH * WW; // 3136

typedef __attribute__((ext_vector_type(8))) short bf16x8;
typedef __attribute__((ext_vector_type(4))) float f32x4;
typedef __attribute__((ext_vector_type(8))) unsigned short u16x8;

__device__ __forceinline__ void glds16(const void* g, void* l) {
    __builtin_amdgcn_global_load_lds((const __attribute__((address_space(1))) void*)g,
                                     (__attribute__((address_space(3))) void*)l, 16, 0, 0);
}

// ---------------- Stage 1 (merged): blocks 0..63 fold BN2 weights (8 o each); blocks 64+ depthwise ----------------
__global__ __launch_bounds__(256) void dwfold_kernel(
    const float* __restrict__ x, const float* __restrict__ dw_w, const float* __restrict__ dw_b,
    const float* __restrict__ g1, const float* __restrict__ b1,
    const float* __restrict__ m1, const float* __restrict__ v1,
    const float* __restrict__ pw_w, const float* __restrict__ pw_b,
    const float* __restrict__ g2, const float* __restrict__ b2,
    const float* __restrict__ m2, const float* __restrict__ v2,
    __hip_bfloat16* __restrict__ y, int* __restrict__ flags,
    __hip_bfloat16* __restrict__ Wf, float* __restrict__ cterm)
{
    __shared__ float xs[58 * 68];
    __shared__ float redw[4];
    const int tid = threadIdx.x;

    if (blockIdx.x < 64) {
        // ---- fold branch: 8 consecutive o rows per block ----
        const int ob = blockIdx.x * 8;
#pragma unroll
        for (int q = 0; q < 8; q++) {
            const int o = ob + q;
            const float inv = g2[o] * rsqrtf(v2[o] + EPSV);
            Wf[o * CIN + tid] = __float2bfloat16(pw_w[o * CIN + tid] * inv);
            if (tid == 0) cterm[o] = (pw_b[o] - m2[o]) * inv + b2[o];
        }
        return;
    }

    // ---- dw branch (VERIFIED R11/R15 compute) ----
    const int blk = blockIdx.x - 64;   // b*CIN + c
    const int c   = blk & (CIN - 1);

    if (tid < 228) {
        int idx;
        if (tid < 58)       idx = 3 + tid;                    // top row 0, cols 3..60
        else if (tid < 116) idx = 57 * 68 + 3 + (tid - 58);   // bottom row 57
        else if (tid < 172) idx = (tid - 116 + 1) * 68 + 3;   // left col, rows 1..56
        else                idx = (tid - 172 + 1) * 68 + 60;  // right col
        xs[idx] = 0.f;
    }
    const float* xp = x + (size_t)blk * HW;
    for (int i = tid; i < 56 * 14; i += 256) {
        int r = i / 14, q = i - r * 14;
        *(f32x4*)&xs[(r + 1) * 68 + 4 + q * 4] = *(const f32x4*)(xp + i * 4);
    }

    float w[9];
#pragma unroll
    for (int k = 0; k < 9; k++) w[k] = dw_w[c * 9 + k];
    const float inv = g1[c] * rsqrtf(v1[c] + EPSV);
    const float sh  = (dw_b[c] - m1[c]) * inv + b1[c];
    __syncthreads();

    float vals[14];
    float mx = 0.f;
    const int row = tid >> 2, strip = tid & 3;
    if (tid < 224) {
        const float* base = xs + row * 68 + strip * 14 + 4;
        float a0 = base[-1],       a1 = base[0];
        float b0 = base[68 - 1],   b1v = base[68];
        float c0 = base[136 - 1],  c1 = base[136];
#pragma unroll
        for (int i = 0; i < 14; i++) {
            const float a2 = base[i + 1];
            const float b2v = base[68 + i + 1];
            const float c2 = base[136 + i + 1];
            float s;
            s = a0 * w[0];
            s = fmaf(a1, w[1], s); s = fmaf(a2, w[2], s);
            s = fmaf(b0, w[3], s); s = fmaf(b1v, w[4], s); s = fmaf(b2v, w[5], s);
            s = fmaf(c0, w[6], s); s = fmaf(c1, w[7], s); s = fmaf(c2, w[8], s);
            const float val = fmaxf(fmaf(s, inv, sh), 0.f);
            vals[i] = val;
            mx = fmaxf(mx, val);
            a0 = a1; a1 = a2; b0 = b1v; b1v = b2v; c0 = c1; c1 = c2;
        }
    }

    for (int off = 32; off > 0; off >>= 1) mx = fmaxf(mx, __shfl_xor(mx, off));
    if ((tid & 63) == 0) redw[tid >> 6] = mx;
    __syncthreads();
    const float bmax = fmaxf(fmaxf(redw[0], redw[1]), fmaxf(redw[2], redw[3]));
    const int survive = (bmax >= DW_THR) ? 1 : 0;
    if (tid == 0) flags[blk] = survive;
    if (survive && tid < 224) {
        unsigned short* yp = (unsigned short*)(y + (size_t)blk * HW) + row * 56 + strip * 14;
#pragma unroll
        for (int i = 0; i < 7; i++) {
            ushort2 pk;
            pk.x = __bfloat16_as_ushort(__float2bfloat16(vals[2 * i]));
            pk.y = __bfloat16_as_ushort(__float2bfloat16(vals[2 * i + 1]));
            *(ushort2*)(yp + 2 * i) = pk;
        }
    }
}

// ---------------- Stage 2: fused-transpose bf16 MFMA GEMM, double-buffered LDS (1 barrier / k-step) ----------------
// block tile 128(o) x 128(n), 4 waves 2x2, wave tile 64x64; K = 256, BK = 32
__global__ __launch_bounds__(256) void gemm_kernel(
    const __hip_bfloat16* __restrict__ Wf_, const __hip_bfloat16* __restrict__ y_,
    const int* __restrict__ flags, const float* __restrict__ cterm,
    float* __restrict__ out)
{
    // XCD-bijective swizzle: 3200 = 8 * 400 -> each XCD gets 4 whole batches
    const int orig = blockIdx.x;
    const int blk  = (orig & 7) * 400 + (orig >> 3);
    const int b    = blk / 100;
    const int rem  = blk % 100;
    const int mt = rem / 25, nt = rem % 25;
    const int tid = threadIdx.x, l = tid & 63, wid = tid >> 6;
    const int wm = wid >> 1, wn = wid & 1;
    const int lr = l & 15, lk = l >> 4;
    const int o0 = mt * 128, n0 = nt * 128;

    __shared__ unsigned short Al[2][128 * 32];  // 2 x 8 KB, XOR slot swizzle (VERIFIED)
    __shared__ unsigned short Bl[2][128 * 34];  // 2 x 8.7 KB, [n][c] rows stride 34 (VERIFIED)
    __shared__ int fl[CIN];

    fl[tid] = flags[b * CIN + tid];

    const short* W = (const short*)Wf_;
    const unsigned short* Y = (const unsigned short*)y_ + (size_t)b * CIN * HW;

    const int kch   = (((l & 3) ^ ((l >> 3) & 3)) << 3);
    const int rowA  = o0 + 32 * wid + (l >> 2);
    const short* asrc0 = W + (size_t)rowA * CIN + kch;
    const short* asrc1 = W + (size_t)(rowA + 16) * CIN + kch;

    const int cp = tid & 15, ng = tid >> 4;
    const int nB = n0 + ng * 8;
    const int nloc = ng * 8;

    f32x4 acc[4][4];   // [nr][mr], transposed D (VERIFIED R8)
#pragma unroll
    for (int nr = 0; nr < 4; nr++)
#pragma unroll
        for (int mr = 0; mr < 4; mr++) acc[nr][mr] = (f32x4){0.f, 0.f, 0.f, 0.f};

    auto STAGE = [&](int t, int s) {
        const int k0 = t * 32;
        glds16(asrc0 + k0, (void*)(&Al[s][(2 * wid) * 512]));
        glds16(asrc1 + k0, (void*)(&Al[s][(2 * wid + 1) * 512]));
        const int c0 = k0 + cp * 2;
        u16x8 v0 = (u16x8){0,0,0,0,0,0,0,0}, v1 = (u16x8){0,0,0,0,0,0,0,0};
        if (fl[c0])     v0 = *(const u16x8*)(Y + (size_t)c0 * HW + nB);
        if (fl[c0 + 1]) v1 = *(const u16x8*)(Y + (size_t)(c0 + 1) * HW + nB);
#pragma unroll
        for (int j = 0; j < 8; j++) {
            const unsigned pk = (unsigned)v0[j] | ((unsigned)v1[j] << 16);
            *(unsigned*)((char*)Bl[s] + (nloc + j) * 68 + cp * 4) = pk;
        }
    };

    __syncthreads();   // fl ready
    STAGE(0, 0);
    __syncthreads();   // buf0 staged

#pragma unroll
    for (int t = 0; t < 8; t++) {
        if (t < 7) STAGE(t + 1, (t + 1) & 1);   // in flight during MFMA(t); drained at loop-end barrier

        const char* alu = (const char*)Al[t & 1];
        const char* blu = (const char*)Bl[t & 1];
        bf16x8 a[4], bb[4];
#pragma unroll
        for (int mr = 0; mr < 4; mr++) {
            const int r = wm * 64 + mr * 16 + lr;
            a[mr] = *(const bf16x8*)(alu + r * 64 + ((lk ^ ((r >> 1) & 3)) << 4));
        }
#pragma unroll
        for (int nr = 0; nr < 4; nr++) {
            const int r = wn * 64 + nr * 16 + lr;
            bb[nr] = *(const bf16x8*)(blu + r * 68 + lk * 16);
        }
#pragma unroll
        for (int nr = 0; nr < 4; nr++)
#pragma unroll
            for (int mr = 0; mr < 4; mr++)
                acc[nr][mr] = __builtin_amdgcn_mfma_f32_16x16x32_bf16(bb[nr], a[mr], acc[nr][mr], 0, 0, 0);
        __syncthreads();   // single barrier: stage(t+1) visible, MFMA(t) reads drained
    }

    // ---- epilogue (VERIFIED R8): + cterm, ReLU, f32x4 NT store ----
    float ct[4];
#pragma unroll
    for (int mr = 0; mr < 4; mr++) ct[mr] = cterm[o0 + wm * 64 + mr * 16 + lr];
    const int nb0 = n0 + wn * 64;
#pragma unroll
    for (int nr = 0; nr < 4; nr++) {
        const int n4 = nb0 + nr * 16 + lk * 4;
        if (n4 < HW) {
#pragma unroll
            for (int mr = 0; mr < 4; mr++) {
                const int o = o0 + wm * 64 + mr * 16 + lr;
                f32x4 z;
                z[0] = fmaxf(acc[nr][mr][0] + ct[mr], 0.f);
                z[1] = fmaxf(acc[nr][mr][1] + ct[mr], 0.f);
                z[2] = fmaxf(acc[nr][mr][2] + ct[mr], 0.f);
                z[3] = fmaxf(acc[nr][mr][3] + ct[mr], 0.f);
                __builtin_nontemporal_store(z, (f32x4*)(out + ((size_t)b * COUT + o) * HW + n4));
            }
        }
    }
}

extern "C" void kernel_launch(void* const* d_in, const int* in_sizes, int n_in,
                              void* d_out, int out_size, void* d_ws, size_t ws_size,
                              hipStream_t stream)
{
    const float* x    = (const float*)d_in[0];
    const float* dw_w = (const float*)d_in[1];
    const float* dw_b = (const float*)d_in[2];
    const float* g1   = (const float*)d_in[3];
    const float* b1   = (const float*)d_in[4];
    const float* m1   = (const float*)d_in[5];
    const float* v1   = (const float*)d_in[6];
    const float* pw_w = (const float*)d_in[7];
    const float* pw_b = (const float*)d_in[8];
    const float* g2   = (const float*)d_in[9];
    const float* b2   = (const float*)d_in[10];
    const float* m2   = (const float*)d_in[11];
    const float* v2   = (const float*)d_in[12];
    float* out = (float*)d_out;

    char* ws = (char*)d_ws;
    size_t off = 0;
    __hip_bfloat16* y  = (__hip_bfloat16*)(ws + off); off += (size_t)BB * CIN * HW * 2 + 256;  // +tail pad (OOB n-tile reads)
    int*   flags = (int*)(ws + off);   off += (size_t)BB * CIN * 4;
    __hip_bfloat16* Wf = (__hip_bfloat16*)(ws + off); off += (size_t)COUT * CIN * 2;
    float* cterm = (float*)(ws + off); off += (size_t)COUT * 4;

    dwfold_kernel<<<64 + BB * CIN, 256, 0, stream>>>(
        x, dw_w, dw_b, g1, b1, m1, v1, pw_w, pw_b, g2, b2, m2, v2, y, flags, Wf, cterm);
    gemm_kernel<<<BB * 4 * 25, 256, 0, stream>>>(Wf, y, flags, cterm, out);
}

// Round 17
// 105.052 us; speedup vs baseline: 1.0852x; 1.0852x over previous
//
#include <hip/hip_runtime.h>
#include <hip/hip_bf16.h>

#define EPSV 1e-5f
#define DW_THR 4.0f
#define PW_THR 1e-3f

static constexpr int BB = 32, CIN = 256, COUT = 512, HH = 56, WW = 56, HW = HH * WW; // 3136

typedef __attribute__((ext_vector_type(8))) short bf16x8;
typedef __attribute__((ext_vector_type(4))) float f32x4;
typedef __attribute__((ext_vector_type(8))) unsigned short u16x8;

__device__ __forceinline__ void glds16(const void* g, void* l) {
    __builtin_amdgcn_global_load_lds((const __attribute__((address_space(1))) void*)g,
                                     (__attribute__((address_space(3))) void*)l, 16, 0, 0);
}

// ---------------- Stage 1 (merged, VERIFIED R15@98.2): fold blocks + dw blocks; NT x loads ----------------
__global__ __launch_bounds__(256) void dwfold_kernel(
    const float* __restrict__ x, const float* __restrict__ dw_w, const float* __restrict__ dw_b,
    const float* __restrict__ g1, const float* __restrict__ b1,
    const float* __restrict__ m1, const float* __restrict__ v1,
    const float* __restrict__ pw_w, const float* __restrict__ pw_b,
    const float* __restrict__ g2, const float* __restrict__ b2,
    const float* __restrict__ m2, const float* __restrict__ v2,
    __hip_bfloat16* __restrict__ y, int* __restrict__ flags,
    __hip_bfloat16* __restrict__ Wf, float* __restrict__ cterm)
{
    __shared__ float xs[58 * 68];
    __shared__ float redw[4];
    const int tid = threadIdx.x;

    if (blockIdx.x < COUT) {
        // ---- fold branch: one block per o ----
        const int o = blockIdx.x;
        const float inv = g2[o] * rsqrtf(v2[o] + EPSV);
        Wf[o * CIN + tid] = __float2bfloat16(pw_w[o * CIN + tid] * inv);
        if (tid == 0) cterm[o] = (pw_b[o] - m2[o]) * inv + b2[o];
        return;
    }

    // ---- dw branch (VERIFIED R11 compute) ----
    const int blk = blockIdx.x - COUT;   // b*CIN + c
    const int c   = blk & (CIN - 1);

    if (tid < 228) {
        int idx;
        if (tid < 58)       idx = 3 + tid;                    // top row 0, cols 3..60
        else if (tid < 116) idx = 57 * 68 + 3 + (tid - 58);   // bottom row 57
        else if (tid < 172) idx = (tid - 116 + 1) * 68 + 3;   // left col, rows 1..56
        else                idx = (tid - 172 + 1) * 68 + 60;  // right col
        xs[idx] = 0.f;
    }
    const float* xp = x + (size_t)blk * HW;
    for (int i = tid; i < 56 * 14; i += 256) {
        int r = i / 14, q = i - r * 14;
        *(f32x4*)&xs[(r + 1) * 68 + 4 + q * 4] =
            __builtin_nontemporal_load((const f32x4*)(xp + i * 4));   // x streamed once: NT
    }

    float w[9];
#pragma unroll
    for (int k = 0; k < 9; k++) w[k] = dw_w[c * 9 + k];
    const float inv = g1[c] * rsqrtf(v1[c] + EPSV);
    const float sh  = (dw_b[c] - m1[c]) * inv + b1[c];
    __syncthreads();

    float vals[14];
    float mx = 0.f;
    const int row = tid >> 2, strip = tid & 3;
    if (tid < 224) {
        const float* base = xs + row * 68 + strip * 14 + 4;
        float a0 = base[-1],       a1 = base[0];
        float b0 = base[68 - 1],   b1v = base[68];
        float c0 = base[136 - 1],  c1 = base[136];
#pragma unroll
        for (int i = 0; i < 14; i++) {
            const float a2 = base[i + 1];
            const float b2v = base[68 + i + 1];
            const float c2 = base[136 + i + 1];
            float s;
            s = a0 * w[0];
            s = fmaf(a1, w[1], s); s = fmaf(a2, w[2], s);
            s = fmaf(b0, w[3], s); s = fmaf(b1v, w[4], s); s = fmaf(b2v, w[5], s);
            s = fmaf(c0, w[6], s); s = fmaf(c1, w[7], s); s = fmaf(c2, w[8], s);
            const float val = fmaxf(fmaf(s, inv, sh), 0.f);
            vals[i] = val;
            mx = fmaxf(mx, val);
            a0 = a1; a1 = a2; b0 = b1v; b1v = b2v; c0 = c1; c1 = c2;
        }
    }

    for (int off = 32; off > 0; off >>= 1) mx = fmaxf(mx, __shfl_xor(mx, off));
    if ((tid & 63) == 0) redw[tid >> 6] = mx;
    __syncthreads();
    const float bmax = fmaxf(fmaxf(redw[0], redw[1]), fmaxf(redw[2], redw[3]));
    const int survive = (bmax >= DW_THR) ? 1 : 0;
    if (tid == 0) flags[blk] = survive;
    if (survive && tid < 224) {
        unsigned short* yp = (unsigned short*)(y + (size_t)blk * HW) + row * 56 + strip * 14;
#pragma unroll
        for (int i = 0; i < 7; i++) {
            ushort2 pk;
            pk.x = __bfloat16_as_ushort(__float2bfloat16(vals[2 * i]));
            pk.y = __bfloat16_as_ushort(__float2bfloat16(vals[2 * i + 1]));
            *(ushort2*)(yp + 2 * i) = pk;
        }
    }
}

// ---------------- Stage 2: fused-transpose LDS-staged bf16 MFMA GEMM (VERIFIED R15@98.2) ----------------
// block tile 128(o) x 128(n), 4 waves 2x2, wave tile 64x64; K = 256, BK = 32
__global__ __launch_bounds__(256) void gemm_kernel(
    const __hip_bfloat16* __restrict__ Wf_, const __hip_bfloat16* __restrict__ y_,
    const int* __restrict__ flags, const float* __restrict__ cterm,
    float* __restrict__ out)
{
    // XCD-bijective swizzle: 3200 = 8 * 400 -> each XCD gets 4 whole batches
    const int orig = blockIdx.x;
    const int blk  = (orig & 7) * 400 + (orig >> 3);
    const int b    = blk / 100;
    const int rem  = blk % 100;
    const int mt = rem / 25, nt = rem % 25;
    const int tid = threadIdx.x, l = tid & 63, wid = tid >> 6;
    const int wm = wid >> 1, wn = wid & 1;
    const int lr = l & 15, lk = l >> 4;
    const int o0 = mt * 128, n0 = nt * 128;

    __shared__ unsigned short Al[128 * 32];  // 8 KB: A rows, XOR slot swizzle
    __shared__ unsigned short Bl[128 * 34];  // 8.7 KB: B rows [n][c], row stride 34 ushorts
    __shared__ int fl[CIN];

    fl[tid] = flags[b * CIN + tid];

    const short* W = (const short*)Wf_;
    const unsigned short* Y = (const unsigned short*)y_ + (size_t)b * CIN * HW;

    const int kch   = (((l & 3) ^ ((l >> 3) & 3)) << 3);
    const int rowA  = o0 + 32 * wid + (l >> 2);
    const short* asrc0 = W + (size_t)rowA * CIN + kch;
    const short* asrc1 = W + (size_t)(rowA + 16) * CIN + kch;

    const int cp = tid & 15, ng = tid >> 4;
    const int nB = n0 + ng * 8;
    const int nloc = ng * 8;

    f32x4 acc[4][4];   // [nr][mr], transposed D
#pragma unroll
    for (int nr = 0; nr < 4; nr++)
#pragma unroll
        for (int mr = 0; mr < 4; mr++) acc[nr][mr] = (f32x4){0.f, 0.f, 0.f, 0.f};

    __syncthreads();   // fl ready

#pragma unroll
    for (int t = 0; t < 8; t++) {
        const int k0 = t * 32;
        glds16(asrc0 + k0, (void*)(&Al[(2 * wid) * 512]));
        glds16(asrc1 + k0, (void*)(&Al[(2 * wid + 1) * 512]));

        const int c0 = k0 + cp * 2;
        u16x8 v0 = (u16x8){0,0,0,0,0,0,0,0}, v1 = (u16x8){0,0,0,0,0,0,0,0};
        if (fl[c0])     v0 = *(const u16x8*)(Y + (size_t)c0 * HW + nB);
        if (fl[c0 + 1]) v1 = *(const u16x8*)(Y + (size_t)(c0 + 1) * HW + nB);
#pragma unroll
        for (int j = 0; j < 8; j++) {
            const unsigned pk = (unsigned)v0[j] | ((unsigned)v1[j] << 16);
            *(unsigned*)((char*)Bl + (nloc + j) * 68 + cp * 4) = pk;
        }
        __syncthreads();

        bf16x8 a[4], bb[4];
#pragma unroll
        for (int mr = 0; mr < 4; mr++) {
            const int r = wm * 64 + mr * 16 + lr;
            a[mr] = *(const bf16x8*)((const char*)Al + r * 64 + ((lk ^ ((r >> 1) & 3)) << 4));
        }
#pragma unroll
        for (int nr = 0; nr < 4; nr++) {
            const int r = wn * 64 + nr * 16 + lr;
            bb[nr] = *(const bf16x8*)((const char*)Bl + r * 68 + lk * 16);
        }
#pragma unroll
        for (int nr = 0; nr < 4; nr++)
#pragma unroll
            for (int mr = 0; mr < 4; mr++)
                acc[nr][mr] = __builtin_amdgcn_mfma_f32_16x16x32_bf16(bb[nr], a[mr], acc[nr][mr], 0, 0, 0);
        __syncthreads();
    }

    // ---- epilogue: + cterm, ReLU, f32x4 NT store ----
    float ct[4];
#pragma unroll
    for (int mr = 0; mr < 4; mr++) ct[mr] = cterm[o0 + wm * 64 + mr * 16 + lr];
    const int nb0 = n0 + wn * 64;
#pragma unroll
    for (int nr = 0; nr < 4; nr++) {
        const int n4 = nb0 + nr * 16 + lk * 4;
        if (n4 < HW) {
#pragma unroll
            for (int mr = 0; mr < 4; mr++) {
                const int o = o0 + wm * 64 + mr * 16 + lr;
                f32x4 z;
                z[0] = fmaxf(acc[nr][mr][0] + ct[mr], 0.f);
                z[1] = fmaxf(acc[nr][mr][1] + ct[mr], 0.f);
                z[2] = fmaxf(acc[nr][mr][2] + ct[mr], 0.f);
                z[3] = fmaxf(acc[nr][mr][3] + ct[mr], 0.f);
                __builtin_nontemporal_store(z, (f32x4*)(out + ((size_t)b * COUT + o) * HW + n4));
            }
        }
    }
}

extern "C" void kernel_launch(void* const* d_in, const int* in_sizes, int n_in,
                              void* d_out, int out_size, void* d_ws, size_t ws_size,
                              hipStream_t stream)
{
    const float* x    = (const float*)d_in[0];
    const float* dw_w = (const float*)d_in[1];
    const float* dw_b = (const float*)d_in[2];
    const float* g1   = (const float*)d_in[3];
    const float* b1   = (const float*)d_in[4];
    const float* m1   = (const float*)d_in[5];
    const float* v1   = (const float*)d_in[6];
    const float* pw_w = (const float*)d_in[7];
    const float* pw_b = (const float*)d_in[8];
    const float* g2   = (const float*)d_in[9];
    const float* b2   = (const float*)d_in[10];
    const float* m2   = (const float*)d_in[11];
    const float* v2   = (const float*)d_in[12];
    float* out = (float*)d_out;

    char* ws = (char*)d_ws;
    size_t off = 0;
    __hip_bfloat16* y  = (__hip_bfloat16*)(ws + off); off += (size_t)BB * CIN * HW * 2 + 256;  // +tail pad (OOB n-tile reads)
    int*   flags = (int*)(ws + off);   off += (size_t)BB * CIN * 4;
    __hip_bfloat16* Wf = (__hip_bfloat16*)(ws + off); off += (size_t)COUT * CIN * 2;
    float* cterm = (float*)(ws + off); off += (size_t)COUT * 4;

    dwfold_kernel<<<COUT + BB * CIN, 256, 0, stream>>>(
        x, dw_w, dw_b, g1, b1, m1, v1, pw_w, pw_b, g2, b2, m2, v2, y, flags, Wf, cterm);
    gemm_kernel<<<BB * 4 * 25, 256, 0, stream>>>(Wf, y, flags, cterm, out);
}

// Round 18
// 98.178 us; speedup vs baseline: 1.1612x; 1.0700x over previous
//
#include <hip/hip_runtime.h>
#include <hip/hip_bf16.h>

#define EPSV 1e-5f
#define DW_THR 4.0f
#define PW_THR 1e-3f

static constexpr int BB = 32, CIN = 256, COUT = 512, HH = 56, WW = 56, HW = HH * WW; // 3136

typedef __attribute__((ext_vector_type(8))) short bf16x8;
typedef __attribute__((ext_vector_type(4))) float f32x4;
typedef __attribute__((ext_vector_type(8))) unsigned short u16x8;

__device__ __forceinline__ void glds16(const void* g, void* l) {
    __builtin_amdgcn_global_load_lds((const __attribute__((address_space(1))) void*)g,
                                     (__attribute__((address_space(3))) void*)l, 16, 0, 0);
}

// ---------------- Stage 1 (merged, VERIFIED R15@98.2): fold blocks + dw blocks ----------------
__global__ __launch_bounds__(256) void dwfold_kernel(
    const float* __restrict__ x, const float* __restrict__ dw_w, const float* __restrict__ dw_b,
    const float* __restrict__ g1, const float* __restrict__ b1,
    const float* __restrict__ m1, const float* __restrict__ v1,
    const float* __restrict__ pw_w, const float* __restrict__ pw_b,
    const float* __restrict__ g2, const float* __restrict__ b2,
    const float* __restrict__ m2, const float* __restrict__ v2,
    __hip_bfloat16* __restrict__ y, int* __restrict__ flags,
    __hip_bfloat16* __restrict__ Wf, float* __restrict__ cterm)
{
    __shared__ float xs[58 * 68];
    __shared__ float redw[4];
    const int tid = threadIdx.x;

    if (blockIdx.x < COUT) {
        // ---- fold branch: one block per o ----
        const int o = blockIdx.x;
        const float inv = g2[o] * rsqrtf(v2[o] + EPSV);
        Wf[o * CIN + tid] = __float2bfloat16(pw_w[o * CIN + tid] * inv);
        if (tid == 0) cterm[o] = (pw_b[o] - m2[o]) * inv + b2[o];
        return;
    }

    // ---- dw branch (VERIFIED R11 compute) ----
    const int blk = blockIdx.x - COUT;   // b*CIN + c
    const int c   = blk & (CIN - 1);

    if (tid < 228) {
        int idx;
        if (tid < 58)       idx = 3 + tid;                    // top row 0, cols 3..60
        else if (tid < 116) idx = 57 * 68 + 3 + (tid - 58);   // bottom row 57
        else if (tid < 172) idx = (tid - 116 + 1) * 68 + 3;   // left col, rows 1..56
        else                idx = (tid - 172 + 1) * 68 + 60;  // right col
        xs[idx] = 0.f;
    }
    const float* xp = x + (size_t)blk * HW;
    for (int i = tid; i < 56 * 14; i += 256) {
        int r = i / 14, q = i - r * 14;
        *(f32x4*)&xs[(r + 1) * 68 + 4 + q * 4] = *(const f32x4*)(xp + i * 4);
    }

    float w[9];
#pragma unroll
    for (int k = 0; k < 9; k++) w[k] = dw_w[c * 9 + k];
    const float inv = g1[c] * rsqrtf(v1[c] + EPSV);
    const float sh  = (dw_b[c] - m1[c]) * inv + b1[c];
    __syncthreads();

    float vals[14];
    float mx = 0.f;
    const int row = tid >> 2, strip = tid & 3;
    if (tid < 224) {
        const float* base = xs + row * 68 + strip * 14 + 4;
        float a0 = base[-1],       a1 = base[0];
        float b0 = base[68 - 1],   b1v = base[68];
        float c0 = base[136 - 1],  c1 = base[136];
#pragma unroll
        for (int i = 0; i < 14; i++) {
            const float a2 = base[i + 1];
            const float b2v = base[68 + i + 1];
            const float c2 = base[136 + i + 1];
            float s;
            s = a0 * w[0];
            s = fmaf(a1, w[1], s); s = fmaf(a2, w[2], s);
            s = fmaf(b0, w[3], s); s = fmaf(b1v, w[4], s); s = fmaf(b2v, w[5], s);
            s = fmaf(c0, w[6], s); s = fmaf(c1, w[7], s); s = fmaf(c2, w[8], s);
            const float val = fmaxf(fmaf(s, inv, sh), 0.f);
            vals[i] = val;
            mx = fmaxf(mx, val);
            a0 = a1; a1 = a2; b0 = b1v; b1v = b2v; c0 = c1; c1 = c2;
        }
    }

    for (int off = 32; off > 0; off >>= 1) mx = fmaxf(mx, __shfl_xor(mx, off));
    if ((tid & 63) == 0) redw[tid >> 6] = mx;
    __syncthreads();
    const float bmax = fmaxf(fmaxf(redw[0], redw[1]), fmaxf(redw[2], redw[3]));
    const int survive = (bmax >= DW_THR) ? 1 : 0;
    if (tid == 0) flags[blk] = survive;
    if (survive && tid < 224) {
        unsigned short* yp = (unsigned short*)(y + (size_t)blk * HW) + row * 56 + strip * 14;
#pragma unroll
        for (int i = 0; i < 7; i++) {
            ushort2 pk;
            pk.x = __bfloat16_as_ushort(__float2bfloat16(vals[2 * i]));
            pk.y = __bfloat16_as_ushort(__float2bfloat16(vals[2 * i + 1]));
            *(ushort2*)(yp + 2 * i) = pk;
        }
    }
}

// ---------------- Stage 2: fused-transpose LDS-staged bf16 MFMA GEMM (VERIFIED R15@98.2) ----------------
// block tile 128(o) x 128(n), 4 waves 2x2, wave tile 64x64; K = 256, BK = 32
__global__ __launch_bounds__(256) void gemm_kernel(
    const __hip_bfloat16* __restrict__ Wf_, const __hip_bfloat16* __restrict__ y_,
    const int* __restrict__ flags, const float* __restrict__ cterm,
    float* __restrict__ out)
{
    // XCD-bijective swizzle: 3200 = 8 * 400 -> each XCD gets 4 whole batches
    const int orig = blockIdx.x;
    const int blk  = (orig & 7) * 400 + (orig >> 3);
    const int b    = blk / 100;
    const int rem  = blk % 100;
    const int mt = rem / 25, nt = rem % 25;
    const int tid = threadIdx.x, l = tid & 63, wid = tid >> 6;
    const int wm = wid >> 1, wn = wid & 1;
    const int lr = l & 15, lk = l >> 4;
    const int o0 = mt * 128, n0 = nt * 128;

    __shared__ unsigned short Al[128 * 32];  // 8 KB: A rows, XOR slot swizzle
    __shared__ unsigned short Bl[128 * 34];  // 8.7 KB: B rows [n][c], row stride 34 ushorts
    __shared__ int fl[CIN];

    fl[tid] = flags[b * CIN + tid];

    const short* W = (const short*)Wf_;
    const unsigned short* Y = (const unsigned short*)y_ + (size_t)b * CIN * HW;

    const int kch   = (((l & 3) ^ ((l >> 3) & 3)) << 3);
    const int rowA  = o0 + 32 * wid + (l >> 2);
    const short* asrc0 = W + (size_t)rowA * CIN + kch;
    const short* asrc1 = W + (size_t)(rowA + 16) * CIN + kch;

    const int cp = tid & 15, ng = tid >> 4;
    const int nB = n0 + ng * 8;
    const int nloc = ng * 8;

    f32x4 acc[4][4];   // [nr][mr], transposed D
#pragma unroll
    for (int nr = 0; nr < 4; nr++)
#pragma unroll
        for (int mr = 0; mr < 4; mr++) acc[nr][mr] = (f32x4){0.f, 0.f, 0.f, 0.f};

    __syncthreads();   // fl ready

#pragma unroll
    for (int t = 0; t < 8; t++) {
        const int k0 = t * 32;
        glds16(asrc0 + k0, (void*)(&Al[(2 * wid) * 512]));
        glds16(asrc1 + k0, (void*)(&Al[(2 * wid + 1) * 512]));

        const int c0 = k0 + cp * 2;
        u16x8 v0 = (u16x8){0,0,0,0,0,0,0,0}, v1 = (u16x8){0,0,0,0,0,0,0,0};
        if (fl[c0])     v0 = *(const u16x8*)(Y + (size_t)c0 * HW + nB);
        if (fl[c0 + 1]) v1 = *(const u16x8*)(Y + (size_t)(c0 + 1) * HW + nB);
#pragma unroll
        for (int j = 0; j < 8; j++) {
            const unsigned pk = (unsigned)v0[j] | ((unsigned)v1[j] << 16);
            *(unsigned*)((char*)Bl + (nloc + j) * 68 + cp * 4) = pk;
        }
        __syncthreads();

        bf16x8 a[4], bb[4];
#pragma unroll
        for (int mr = 0; mr < 4; mr++) {
            const int r = wm * 64 + mr * 16 + lr;
            a[mr] = *(const bf16x8*)((const char*)Al + r * 64 + ((lk ^ ((r >> 1) & 3)) << 4));
        }
#pragma unroll
        for (int nr = 0; nr < 4; nr++) {
            const int r = wn * 64 + nr * 16 + lr;
            bb[nr] = *(const bf16x8*)((const char*)Bl + r * 68 + lk * 16);
        }
#pragma unroll
        for (int nr = 0; nr < 4; nr++)
#pragma unroll
            for (int mr = 0; mr < 4; mr++)
                acc[nr][mr] = __builtin_amdgcn_mfma_f32_16x16x32_bf16(bb[nr], a[mr], acc[nr][mr], 0, 0, 0);
        __syncthreads();
    }

    // ---- epilogue: + cterm, ReLU, f32x4 NT store ----
    float ct[4];
#pragma unroll
    for (int mr = 0; mr < 4; mr++) ct[mr] = cterm[o0 + wm * 64 + mr * 16 + lr];
    const int nb0 = n0 + wn * 64;
#pragma unroll
    for (int nr = 0; nr < 4; nr++) {
        const int n4 = nb0 + nr * 16 + lk * 4;
        if (n4 < HW) {
#pragma unroll
            for (int mr = 0; mr < 4; mr++) {
                const int o = o0 + wm * 64 + mr * 16 + lr;
                f32x4 z;
                z[0] = fmaxf(acc[nr][mr][0] + ct[mr], 0.f);
                z[1] = fmaxf(acc[nr][mr][1] + ct[mr], 0.f);
                z[2] = fmaxf(acc[nr][mr][2] + ct[mr], 0.f);
                z[3] = fmaxf(acc[nr][mr][3] + ct[mr], 0.f);
                __builtin_nontemporal_store(z, (f32x4*)(out + ((size_t)b * COUT + o) * HW + n4));
            }
        }
    }
}

extern "C" void kernel_launch(void* const* d_in, const int* in_sizes, int n_in,
                              void* d_out, int out_size, void* d_ws, size_t ws_size,
                              hipStream_t stream)
{
    const float* x    = (const float*)d_in[0];
    const float* dw_w = (const float*)d_in[1];
    const float* dw_b = (const float*)d_in[2];
    const float* g1   = (const float*)d_in[3];
    const float* b1   = (const float*)d_in[4];
    const float* m1   = (const float*)d_in[5];
    const float* v1   = (const float*)d_in[6];
    const float* pw_w = (const float*)d_in[7];
    const float* pw_b = (const float*)d_in[8];
    const float* g2   = (const float*)d_in[9];
    const float* b2   = (const float*)d_in[10];
    const float* m2   = (const float*)d_in[11];
    const float* v2   = (const float*)d_in[12];
    float* out = (float*)d_out;

    char* ws = (char*)d_ws;
    size_t off = 0;
    __hip_bfloat16* y  = (__hip_bfloat16*)(ws + off); off += (size_t)BB * CIN * HW * 2 + 256;  // +tail pad (OOB n-tile reads)
    int*   flags = (int*)(ws + off);   off += (size_t)BB * CIN * 4;
    __hip_bfloat16* Wf = (__hip_bfloat16*)(ws + off); off += (size_t)COUT * CIN * 2;
    float* cterm = (float*)(ws + off); off += (size_t)COUT * 4;

    dwfold_kernel<<<COUT + BB * CIN, 256, 0, stream>>>(
        x, dw_w, dw_b, g1, b1, m1, v1, pw_w, pw_b, g2, b2, m2, v2, y, flags, Wf, cterm);
    gemm_kernel<<<BB * 4 * 25, 256, 0, stream>>>(Wf, y, flags, cterm, out);
}